// Round 2
// baseline (586.929 us; speedup 1.0000x reference)
//
#include <hip/hip_runtime.h>
#include <stdint.h>

#define HW   50176
#define IMW  224
#define NS   4096
#define EPSF 1e-6f

// ---------------- helpers ----------------
__device__ __forceinline__ bool finitef(float x){
  return (__float_as_uint(x) & 0x7f800000u) != 0x7f800000u;
}
__device__ __forceinline__ uint32_t ordenc(float f){
  uint32_t u = __float_as_uint(f);
  return (u & 0x80000000u) ? ~u : (u | 0x80000000u);
}
__device__ __forceinline__ float orddec(uint32_t e){
  uint32_t u = (e & 0x80000000u) ? (e & 0x7fffffffu) : ~e;
  return __uint_as_float(u);
}
__device__ __forceinline__ int wsum_i(int v){
  #pragma unroll
  for (int o=32;o;o>>=1) v += __shfl_down(v,o);
  return v;
}
__device__ __forceinline__ float wsum_f(float v){
  #pragma unroll
  for (int o=32;o;o>>=1) v += __shfl_down(v,o);
  return v;
}
__device__ __forceinline__ float block_sum_f(float v, float* lds){
  v = wsum_f(v);
  int nw = blockDim.x >> 6;
  __syncthreads();
  if ((threadIdx.x & 63)==0) lds[threadIdx.x>>6] = v;
  __syncthreads();
  if (threadIdx.x==0){ float s=0.f; for (int k=0;k<nw;k++) s+=lds[k]; lds[16]=s; }
  __syncthreads();
  return lds[16];
}

// Workspace float layout:
// [0] pose_loss  [1] depth_abs_sum  [3] normal_sum
// [4..7] pg_sum[f]  [8..11] gp_sum[f]  [12..15] selwsum[f]
// [16..19] maskcnt[f] (float)  [20..23] scale[f]
// ints I = (int*)(W+24):
//   I[0..3] selcnt  I[4..7] nn  I[8..11] mc  I[12..15] candcnt  I[16..19] kcandcnt
//   I[20..23] b1  I[24..27] r1  I[28..31] b2  I[32..35] r2  I[36..39] bk  I[40..43] rk
// [72..119] relgt[f][12]  (R row-major 9, then t 3)
// [256..16639]      SEL  (int, 4*4096)
// [16640..82175]    PS   (float4, 4*4096)   -- overlaid pre-gather: HIST (uint 4*16384)
// [82176..147711]   GS   (float4, 4*4096)   -- overlaid pre-gather: KHIST(8192) CAND(16384) KCAND(16384)
// [147712..180479]  RMIN (uint32 ordered-float, 2*4*4096) -- init'd in k_gather
#define OFF_SEL  256
#define OFF_PS   16640
#define OFF_GS   82176
#define OFF_RMIN 147712
#define NRB 16384   // ratio hist buckets/frame (top 14 bits)
#define NKB 2048    // key hist buckets/frame  (top 11 of 21 bits)

// ---------------- init: zero control + histograms ----------------
__global__ void k_init(float* W){
  int gid = blockIdx.x*256 + threadIdx.x;           // 65536 threads
  ((uint32_t*)(W + OFF_PS))[gid] = 0u;              // HIST
  if (gid < 4*NKB) ((uint32_t*)(W + OFF_GS))[gid] = 0u;  // KHIST
  if (gid < 256) W[gid] = 0.f;
}

// ---------------- pose helpers ----------------
__device__ void inv4(const float* A, float* out){
  float M[4][8];
  for (int i=0;i<4;i++) for (int j=0;j<4;j++){ M[i][j]=A[i*4+j]; M[i][4+j]=(i==j)?1.f:0.f; }
  for (int c=0;c<4;c++){
    int piv=c; float mx=fabsf(M[c][c]);
    for (int r=c+1;r<4;r++){ float a=fabsf(M[r][c]); if (a>mx){ mx=a; piv=r; } }
    if (piv!=c) for (int j=0;j<8;j++){ float t=M[c][j]; M[c][j]=M[piv][j]; M[piv][j]=t; }
    float inv = 1.f/M[c][c];
    for (int j=0;j<8;j++) M[c][j]*=inv;
    for (int r=0;r<4;r++){
      if (r==c) continue;
      float fv = M[r][c];
      for (int j=0;j<8;j++) M[r][j] -= fv*M[c][j];
    }
  }
  for (int i=0;i<4;i++) for (int j=0;j<4;j++) out[i*4+j]=M[i][4+j];
}
__device__ void mat4(const float* A, const float* B, float* C){
  for (int i=0;i<4;i++) for (int j=0;j<4;j++){
    float s=0.f;
    for (int k=0;k<4;k++) s += A[i*4+k]*B[k*4+j];
    C[i*4+j]=s;
  }
}

// ---------------- pass 1: histograms + counts ----------------
__global__ __launch_bounds__(256) void k_hist(const float* dp_, const float* dg_, float* W){
  int b = blockIdx.x;                 // 784 blocks; 196 per frame
  int f = b / 196;
  int r = (b - f*196)*256 + threadIdx.x;
  float dgv = dg_[f*HW + r], dpv = dp_[f*HW + r];
  bool mg = (dgv > EPSF) && finitef(dgv);
  bool m  = mg && finitef(dpv) && (dpv > EPSF);
  uint32_t* HIST  = (uint32_t*)(W + OFF_PS);
  uint32_t* KHIST = (uint32_t*)(W + OFF_GS);
  int* I = (int*)(W + 24);
  if (m){
    uint32_t u = __float_as_uint(dpv / fmaxf(dgv, EPSF));
    atomicAdd(&HIST[f*NRB + (u>>18)], 1u);
  }
  uint32_t jit = ((uint32_t)r * 2654435761u) & 0xFFFFFu;
  uint32_t key = ((uint32_t)(mg?1:0) << 20) | jit;
  atomicAdd(&KHIST[f*NKB + (key>>10)], 1u);
  int nn_l = wsum_i(m ? 1 : 0);
  int mc_l = wsum_i(mg ? 1 : 0);
  if ((threadIdx.x & 63) == 0){
    atomicAdd(&I[4+f], nn_l);
    atomicAdd(&I[8+f], mc_l);
  }
}

// ---------------- pass 2: prefix over histograms -> bucket+rank (+pose in block 4) ----------------
__global__ __launch_bounds__(1024) void k_scan(const float* pp, const float* pg, float* W){
  if (blockIdx.x == 4){
    if (threadIdx.x != 0) return;
    float i0p[16], i0g[16];
    inv4(pp, i0p); inv4(pg, i0g);
    float s=0.f;
    for (int f=0; f<4; f++){
      float rp[16], rg[16];
      mat4(i0p, pp+16*f, rp);
      mat4(i0g, pg+16*f, rg);
      for (int k=0;k<16;k++) s += fabsf(rp[k]-rg[k]);
      for (int i=0;i<3;i++) for (int j=0;j<3;j++) W[72+f*12+i*3+j]=rg[i*4+j];
      for (int i=0;i<3;i++) W[72+f*12+9+i]=rg[i*4+3];
    }
    W[0] = s/64.f;
    return;
  }
  const int f = blockIdx.x, tid = threadIdx.x;
  __shared__ int lds[1024];
  int* I = (int*)(W + 24);
  const uint32_t* HIST  = (const uint32_t*)(W + OFF_PS) + f*NRB;
  const uint32_t* KHIST = (const uint32_t*)(W + OFF_GS) + f*NKB;

  int nn = I[4+f];
  if (nn > 0){
    int loc[16], part = 0;
    #pragma unroll
    for (int j=0;j<16;j++){ loc[j] = (int)HIST[tid*16+j]; part += loc[j]; }
    lds[tid] = part; __syncthreads();
    for (int off=1; off<1024; off<<=1){
      int add = (tid>=off) ? lds[tid-off] : 0;
      __syncthreads();
      lds[tid] += add;
      __syncthreads();
    }
    int base = lds[tid] - part;
    int k1 = (nn-1)>>1, k2 = nn>>1;
    int acc = base;
    #pragma unroll
    for (int j=0;j<16;j++){
      int c = loc[j];
      if (k1 >= acc && k1 < acc+c){ I[20+f] = tid*16+j; I[24+f] = k1-acc; }
      if (k2 >= acc && k2 < acc+c){ I[28+f] = tid*16+j; I[32+f] = k2-acc; }
      acc += c;
    }
  } else if (tid == 0){
    I[20+f] = -1; I[28+f] = -1;
  }
  __syncthreads();

  {
    int l0 = (int)KHIST[tid*2], l1 = (int)KHIST[tid*2+1];
    int part = l0 + l1;
    lds[tid] = part; __syncthreads();
    for (int off=1; off<1024; off<<=1){
      int add = (tid>=off) ? lds[tid-off] : 0;
      __syncthreads();
      lds[tid] += add;
      __syncthreads();
    }
    int base = lds[tid] - part;
    const int t = HW - NS;
    int acc = base;
    if (t >= acc && t < acc+l0){ I[36+f] = tid*2;   I[40+f] = t-acc; }
    acc += l0;
    if (t >= acc && t < acc+l1){ I[36+f] = tid*2+1; I[40+f] = t-acc; }
  }
}

// ---------------- pass 3: collect boundary candidates + bulk selection ----------------
__global__ __launch_bounds__(256) void k_collect(const float* dp_, const float* dg_, float* W){
  int b = blockIdx.x;
  int f = b / 196;
  int r = (b - f*196)*256 + threadIdx.x;
  float dgv = dg_[f*HW + r], dpv = dp_[f*HW + r];
  bool mg = (dgv > EPSF) && finitef(dgv);
  bool m  = mg && finitef(dpv) && (dpv > EPSF);
  int* I = (int*)(W + 24);
  uint32_t* CAND  = (uint32_t*)(W + OFF_GS) + 4*NKB;
  uint32_t* KCAND = CAND + 16384;
  int* SEL = (int*)(W + OFF_SEL);
  int b1 = I[20+f], b2 = I[28+f], bk = I[36+f];

  if (m){
    uint32_t u = __float_as_uint(dpv / fmaxf(dgv, EPSF));
    int bu = (int)(u>>18);
    if (bu == b1 || bu == b2){
      int p = atomicAdd(&I[12+f], 1);
      if (p < 4096) CAND[f*4096 + p] = u;
    }
  }
  uint32_t jit = ((uint32_t)r * 2654435761u) & 0xFFFFFu;
  uint32_t key = ((uint32_t)(mg?1:0) << 20) | jit;
  int kb = (int)(key>>10);
  bool sel = kb > bk;
  unsigned long long ball = __ballot(sel);
  if (sel){
    int lane = threadIdx.x & 63;
    int myoff = __popcll(ball & ((1ull<<lane)-1ull));
    int leader = __builtin_ctzll(ball);
    int base = 0;
    if (lane == leader) base = atomicAdd(&I[0+f], __popcll(ball));
    base = __shfl(base, leader);
    SEL[(f<<12) + base + myoff] = r;
  }
  if (kb == bk){
    int p = atomicAdd(&I[16+f], 1);
    if (p < 4096) KCAND[f*4096 + p] = (uint32_t)r;
  }
}

// ---------------- pass 4: exact median + exact key threshold ----------------
__global__ __launch_bounds__(256) void k_finish(float* W){
  const int f = blockIdx.x, tid = threadIdx.x;
  int* I = (int*)(W + 24);
  uint32_t* CAND  = (uint32_t*)(W + OFF_GS) + 4*NKB;
  uint32_t* KCAND = CAND + 16384;
  int* SEL = (int*)(W + OFF_SEL);
  __shared__ uint32_t sv1, sv2;
  if (tid == 0){ sv1 = 0u; sv2 = 0u; }
  __syncthreads();

  int nn = I[4+f], mc = I[8+f];
  if (nn > 0){
    int b1 = I[20+f], r1 = I[24+f], b2 = I[28+f], r2 = I[32+f];
    int nc = min(I[12+f], 4096);
    for (int t = tid; t < nc; t += 256){
      uint32_t c = CAND[f*4096 + t];
      int bu = (int)(c>>18);
      if (bu == b1){
        int less = 0, eq = 0;
        for (int j=0;j<nc;j++){
          uint32_t d = CAND[f*4096 + j];
          if ((int)(d>>18) == b1){ less += (d < c); eq += (d == c); }
        }
        if (r1 >= less && r1 < less+eq) sv1 = c;
      }
      if (bu == b2){
        int less = 0, eq = 0;
        for (int j=0;j<nc;j++){
          uint32_t d = CAND[f*4096 + j];
          if ((int)(d>>18) == b2){ less += (d < c); eq += (d == c); }
        }
        if (r2 >= less && r2 < less+eq) sv2 = c;
      }
    }
  }
  __syncthreads();
  if (tid == 0){
    float scale = 1.f;
    if (nn > 0){
      float med = 0.5f*(__uint_as_float(sv1) + __uint_as_float(sv2));
      scale = (nn < 16 || !finitef(med)) ? 1.f : fminf(fmaxf(med, 1e-3f), 1e3f);
    }
    W[20+f] = scale;
    W[16+f] = (float)mc;
  }

  int bk = I[36+f], rk = I[40+f];
  int nk = min(I[16+f], 4096);
  uint32_t maskbit = ((uint32_t)bk >> 10) & 1u;
  for (int t = tid; t < nk; t += 256){
    uint32_t i = KCAND[f*4096 + t];
    uint32_t key = (maskbit<<20) | ((i*2654435761u) & 0xFFFFFu);
    int rank = 0;
    for (int j=0;j<nk;j++){
      uint32_t i2 = KCAND[f*4096 + j];
      uint32_t key2 = (maskbit<<20) | ((i2*2654435761u) & 0xFFFFFu);
      rank += (key2 < key);
    }
    if (rank >= rk){
      int p = atomicAdd(&I[0+f], 1);
      SEL[(f<<12) + p] = (int)i;
    }
  }
}

// ---------------- gather selected pred/gt world points (+ RMIN init) ----------------
__global__ __launch_bounds__(256) void k_gather(const float* points_pred, const float* depth_gt,
                                                const float* intr, float* W){
  int gid = blockIdx.x*256 + threadIdx.x;      // 16384
  uint32_t* RM = (uint32_t*)(W + OFF_RMIN);
  RM[gid] = 0xFF800000u;                        // ordenc(+inf)
  RM[gid + 16384] = 0xFF800000u;
  int f = gid >> 12;
  const int* SEL = (const int*)(W + OFF_SEL);
  int idx = SEL[gid];
  float dgv = depth_gt[f*HW + idx];
  bool mg = (dgv > EPSF) && finitef(dgv);
  float wv = mg ? 1.f : 0.f;

  const float* p = points_pred + (size_t)(f*HW + idx)*3;
  float4 ps; ps.x=p[0]; ps.y=p[1]; ps.z=p[2]; ps.w=wv;
  ((float4*)(W + OFF_PS))[gid] = ps;

  float sc = W[20+f];
  float d = dgv * sc;
  float fx = fmaxf(intr[f*9+0], EPSF), fy = fmaxf(intr[f*9+4], EPSF);
  float cx = intr[f*9+2], cy = intr[f*9+5];
  int y = idx / IMW, x = idx - y*IMW;
  float X = ((float)x - cx)/fx * d;
  float Y = ((float)y - cy)/fy * d;
  float Z = d;
  const float* R = W + 72 + f*12;
  float4 gs;
  gs.x = R[0]*X + R[1]*Y + R[2]*Z + R[9];
  gs.y = R[3]*X + R[4]*Y + R[5]*Z + R[10];
  gs.z = R[6]*X + R[7]*Y + R[8]*Z + R[11];
  gs.w = wv;
  ((float4*)(W + OFF_GS))[gid] = gs;

  float wsum = wsum_f(wv);
  if ((threadIdx.x & 63) == 0) atomicAdd(&W[12+f], wsum);
}

// ---------------- chamfer row-min (both directions) ----------------
__global__ __launch_bounds__(256) void k_cham(float* W){
  const int f = blockIdx.y, dir = blockIdx.z;
  const int rc = blockIdx.x & 7, gc = blockIdx.x >> 3;
  const float4* PS = (const float4*)(W + OFF_PS);
  const float4* GS = (const float4*)(W + OFF_GS);
  const float4* A = dir ? GS : PS;
  const float4* B = dir ? PS : GS;
  uint32_t* RM = (uint32_t*)(W + OFF_RMIN) + dir*16384 + (f<<12);

  __shared__ float4 tile[512];
  int tid = threadIdx.x;
  for (int j=tid; j<512; j+=256){
    float4 b = B[(f<<12) + (gc<<9) + j];
    float gg = b.x*b.x + b.y*b.y + b.z*b.z;
    tile[j] = make_float4(b.x, b.y, b.z, (b.w > 0.f) ? gg : -1.f);
  }
  __syncthreads();

  int r0 = (rc<<9) + tid, r1 = r0 + 256;
  float4 a0 = A[(f<<12)+r0], a1 = A[(f<<12)+r1];
  float pp0 = a0.x*a0.x + a0.y*a0.y + a0.z*a0.z;
  float pp1 = a1.x*a1.x + a1.y*a1.y + a1.z*a1.z;
  float m0 = INFINITY, m1 = INFINITY;
  #pragma unroll 8
  for (int j=0;j<512;++j){
    float4 g = tile[j];
    float dt0 = fmaf(a0.x,g.x, fmaf(a0.y,g.y, a0.z*g.z));
    float dt1 = fmaf(a1.x,g.x, fmaf(a1.y,g.y, a1.z*g.z));
    if (g.w >= 0.f){
      m0 = fminf(m0, fmaf(-2.f, dt0, pp0 + g.w));
      m1 = fminf(m1, fmaf(-2.f, dt1, pp1 + g.w));
    }
  }
  atomicMin(&RM[r0], ordenc(m0));
  atomicMin(&RM[r1], ordenc(m1));
}

// ---------------- chamfer finish: sqrt + weighted sum ----------------
__global__ __launch_bounds__(256) void k_chamfin(float* W){
  __shared__ float flds[17];
  int gid = blockIdx.x*256 + threadIdx.x;      // 32768
  int dir = gid >> 14;
  int rem = gid & 16383;
  int f = rem >> 12;
  int row = rem & 4095;
  float val = orddec(((uint32_t*)(W + OFF_RMIN))[gid]);
  float d = isinf(val) ? 1e9f : sqrtf(fmaxf(val, 1e-12f));
  const float4* A = dir ? (const float4*)(W + OFF_GS) : (const float4*)(W + OFF_PS);
  float w = A[(f<<12)+row].w;
  float c = block_sum_f(d*w, flds);
  if (threadIdx.x==0) atomicAdd(&W[4 + dir*4 + f], c);
}

// ---------------- normals + depth L1 (fused) ----------------
__device__ __forceinline__ float3 normal_at(const float* D, float sc, int x, int y,
                                            float cx, float cy, float fx, float fy){
  int base = y*IMW + x;
  float dL = D[base-1]*sc,   dR = D[base+1]*sc;
  float dU = D[base-IMW]*sc, dD = D[base+IMW]*sc;
  float xl = ((float)(x-1)-cx)/fx, xr = ((float)(x+1)-cx)/fx, xc = ((float)x-cx)/fx;
  float yu = ((float)(y-1)-cy)/fy, yd = ((float)(y+1)-cy)/fy, yc = ((float)y-cy)/fy;
  float ax = xc*dD - xc*dU, ay = yd*dD - yu*dU, az = dD - dU;
  float bx = xr*dR - xl*dL, by = yc*dR - yc*dL, bz = dR - dL;
  float nx = ay*bz - az*by;
  float ny = az*bx - ax*bz;
  float nz = ax*by - ay*bx;
  float l = sqrtf(nx*nx + ny*ny + nz*nz);
  float inv = 1.f/fmaxf(l, EPSF);
  return make_float3(nx*inv, ny*inv, nz*inv);
}

__global__ __launch_bounds__(256) void k_normdep(const float* dp_, const float* dg_,
                                                 const float* intr, float* W){
  __shared__ float flds[17];
  int gid = blockIdx.x*256 + threadIdx.x;      // 200704
  int f = gid / HW;
  int r = gid - f*HW;
  int y = r / IMW, x = r - y*IMW;
  float dgv = dg_[gid], dpv = dp_[gid];
  bool mg = (dgv > EPSF) && finitef(dgv);
  float mv = mg ? 1.f : 0.f;
  float sc = W[20+f];
  float dsum = fabsf(dpv - dgv*sc) * mv;

  float nsum;
  if (x > 0 && x < IMW-1 && y > 0 && y < IMW-1){
    float fx = fmaxf(intr[f*9+0], EPSF), fy = fmaxf(intr[f*9+4], EPSF);
    float cx = intr[f*9+2], cy = intr[f*9+5];
    float3 n1 = normal_at(dp_ + f*HW, 1.f, x, y, cx, cy, fx, fy);
    float3 n2 = normal_at(dg_ + f*HW, sc,  x, y, cx, cy, fx, fy);
    float l1 = sqrtf(n1.x*n1.x + n1.y*n1.y + n1.z*n1.z);
    float l2 = sqrtf(n2.x*n2.x + n2.y*n2.y + n2.z*n2.z);
    float i1 = 1.f/fmaxf(l1, EPSF), i2 = 1.f/fmaxf(l2, EPSF);
    float cosv = (n1.x*n2.x + n1.y*n2.y + n1.z*n2.z)*i1*i2;
    cosv = fminf(fmaxf(cosv, -1.f), 1.f);
    nsum = (1.f - cosv) * mv;
  } else {
    nsum = mv;
  }
  float ds = block_sum_f(dsum, flds);
  float ns = block_sum_f(nsum, flds);
  if (threadIdx.x==0){
    atomicAdd(&W[1], ds);
    atomicAdd(&W[3], ns);
  }
}

// ---------------- final combine ----------------
__global__ void k_final(const float* W, float* out){
  if (threadIdx.x!=0 || blockIdx.x!=0) return;
  float md = fmaxf(W[16]+W[17]+W[18]+W[19], 1.f);
  float depth_loss = W[1]/md;
  float normal_loss = W[3]/md;
  float cds=0.f, oks=0.f;
  for (int f=0; f<4; f++){
    if (W[16+f] >= 10.f){
      float denom = fmaxf(W[12+f], 1.f);
      cds += W[4+f]/denom + W[8+f]/denom;
      oks += 1.f;
    }
  }
  float points_loss = cds / fmaxf(oks, 1.f);
  out[0] = W[0] + depth_loss + points_loss + normal_loss;
}

extern "C" void kernel_launch(void* const* d_in, const int* in_sizes, int n_in,
                              void* d_out, int out_size, void* d_ws, size_t ws_size,
                              hipStream_t stream){
  const float* depth_pred  = (const float*)d_in[0];
  const float* points_pred = (const float*)d_in[1];
  const float* depth_gt    = (const float*)d_in[2];
  const float* intr        = (const float*)d_in[3];
  const float* pose_pred   = (const float*)d_in[4];
  const float* pose_gt     = (const float*)d_in[5];
  float* out = (float*)d_out;
  float* W   = (float*)d_ws;

  k_init   <<<256, 256, 0, stream>>>(W);
  k_hist   <<<784, 256, 0, stream>>>(depth_pred, depth_gt, W);
  k_scan   <<<5, 1024, 0, stream>>>(pose_pred, pose_gt, W);
  k_collect<<<784, 256, 0, stream>>>(depth_pred, depth_gt, W);
  k_finish <<<4, 256, 0, stream>>>(W);
  k_gather <<<64, 256, 0, stream>>>(points_pred, depth_gt, intr, W);
  k_cham   <<<dim3(64,4,2), 256, 0, stream>>>(W);
  k_chamfin<<<128, 256, 0, stream>>>(W);
  k_normdep<<<784, 256, 0, stream>>>(depth_pred, depth_gt, intr, W);
  k_final  <<<1, 1, 0, stream>>>(W, out);
}